// Round 1
// baseline (174.756 us; speedup 1.0000x reference)
//
#include <hip/hip_runtime.h>
#include <math.h>

// Problem constants
#define NB 4
#define NT 32
#define NBT 128     // NB*NT
#define NH 128
#define NW 128

// Workspace float offsets
#define FQ_OFF    0        // 128 images * 512 modes * 2 = 131072 floats
#define FK_OFF    131072
#define FVC_OFF   262144
#define PHIQ_OFF  393216   // 128 * 1024
#define PHIK_OFF  524288
#define KX_OFF    655360   // 4096
#define OUT_KX_OFF 4194304 // offset of kx in d_out (after 4*32*256*128 output)

// ---------------------------------------------------------------------------
// K1: forward restricted DFT of x and y images, apply spectral weights,
//     build phi feature vectors (Parseval-equivalent of pixel fields).
// grid: 256 blocks (img 0..127 = x images -> Fq,Fk,phi; 128..255 = y -> Fvc)
// block: 256 threads. One image per block.
// ---------------------------------------------------------------------------
__global__ __launch_bounds__(256) void fwd_kernel(
    const float* __restrict__ z,
    const float* __restrict__ qw1r, const float* __restrict__ qw1i,
    const float* __restrict__ qw2r, const float* __restrict__ qw2i,
    const float* __restrict__ kw1r, const float* __restrict__ kw1i,
    const float* __restrict__ kw2r, const float* __restrict__ kw2i,
    const float* __restrict__ icl,  const float* __restrict__ ker,
    float* __restrict__ ws)
{
    __shared__ float ct[128], st[128];
    __shared__ float rows[16 * 129];
    __shared__ float Gr[128 * 17], Gi[128 * 17];
    __shared__ float f0r[64], f0i[64];   // v=0 columns: [0:32]=q set, [32:64]=k set

    const int tid = threadIdx.x;
    const int img = blockIdx.x;
    const int bt  = img & 127;
    const int isY = img >> 7;

    if (tid < 128) {
        float ang = (float)tid * 0.049087385212340517f;  // 2*pi/128
        float s, c;
        sincosf(ang, &s, &c);
        ct[tid] = c; st[tid] = s;
    }
    __syncthreads();

    const float* xim = z + ((size_t)bt * 256 + (size_t)isY * 128) * 128;

    const int v   = tid & 15;   // 0..15
    const int hl  = tid >> 4;   // 0..15 (row within chunk / ui group)

    // ---- Phase 1: G[h][v] = sum_w x[h][w] e^{-2pi i v w/128} ----
    for (int c0 = 0; c0 < 8; ++c0) {
        for (int k2 = tid; k2 < 2048; k2 += 256) {
            int r = k2 >> 7, cc = k2 & 127;
            rows[r * 129 + cc] = xim[(size_t)(c0 * 16 + r) * 128 + cc];
        }
        __syncthreads();
        float gr = 0.f, gi = 0.f;
        const float* rp = rows + hl * 129;
        for (int w = 0; w < 128; ++w) {
            float val = rp[w];
            int k = (v * w) & 127;
            gr = fmaf(val, ct[k], gr);
            gi = fmaf(val, st[k], gi);
        }
        int h = c0 * 16 + hl;
        Gr[h * 17 + v] = gr;
        Gi[h * 17 + v] = -gi;   // e^{-i theta}
        __syncthreads();
    }

    // ---- Phase 2: M[u][v] = sum_h G[h][v] e^{-2pi i u h/128}, two u per thread
    const int ui0 = hl;          // 0..15 -> actual u = ui0
    const int u1  = ui0 + 112;   // actual u for ui0+16
    float m0r = 0.f, m0i = 0.f, m1r = 0.f, m1i = 0.f;
    for (int h = 0; h < 128; ++h) {
        float grv = Gr[h * 17 + v], giv = Gi[h * 17 + v];
        int k0 = (ui0 * h) & 127;
        float c0v = ct[k0], s0v = st[k0];
        // (gr + i gi)(cos - i sin) = (gr c + gi s) + i(gi c - gr s)
        m0r = fmaf(grv, c0v, fmaf(giv,  s0v, m0r));
        m0i = fmaf(giv, c0v, fmaf(-grv, s0v, m0i));
        int k1 = (u1 * h) & 127;
        float c1v = ct[k1], s1v = st[k1];
        m1r = fmaf(grv, c1v, fmaf(giv,  s1v, m1r));
        m1i = fmaf(giv, c1v, fmaf(-grv, s1v, m1i));
    }

    const int mi  = ui0 * 16 + v;        // weight index (same for w1 and w2)
    const int g0  = mi;                  // mode slot (ui0, v)
    const int g1  = (ui0 + 16) * 16 + v; // mode slot (ui0+16, v)

    if (!isY) {
        // ---- x image: Fq = M*qw, Fk = M*kw ----
        float a = qw1r[mi], bq = qw1i[mi];
        float fqr0 = m0r * a - m0i * bq;
        float fqi0 = m0r * bq + m0i * a;
        a = qw2r[mi]; bq = qw2i[mi];
        float fqr1 = m1r * a - m1i * bq;
        float fqi1 = m1r * bq + m1i * a;
        a = kw1r[mi]; bq = kw1i[mi];
        float fkr0 = m0r * a - m0i * bq;
        float fki0 = m0r * bq + m0i * a;
        a = kw2r[mi]; bq = kw2i[mi];
        float fkr1 = m1r * a - m1i * bq;
        float fki1 = m1r * bq + m1i * a;

        float* FQ = ws + FQ_OFF + (size_t)bt * 1024;
        float* FK = ws + FK_OFF + (size_t)bt * 1024;
        FQ[g0 * 2] = fqr0; FQ[g0 * 2 + 1] = fqi0;
        FQ[g1 * 2] = fqr1; FQ[g1 * 2 + 1] = fqi1;
        FK[g0 * 2] = fkr0; FK[g0 * 2 + 1] = fki0;
        FK[g1 * 2] = fkr1; FK[g1 * 2 + 1] = fki1;

        // ---- phi features ----
        float* PQ = ws + PHIQ_OFF + (size_t)bt * 1024;
        float* PK = ws + PHIK_OFF + (size_t)bt * 1024;
        const float c2 = 0.011048543456039806f;  // sqrt(2)/128
        if (v >= 1) {
            int b0 = ((v - 1) * 32 + ui0) * 2;
            int b1 = ((v - 1) * 32 + ui0 + 16) * 2;
            PQ[b0] = c2 * fqr0; PQ[b0 + 1] = c2 * fqi0;
            PQ[b1] = c2 * fqr1; PQ[b1 + 1] = c2 * fqi1;
            PK[b0] = c2 * fkr0; PK[b0 + 1] = c2 * fki0;
            PK[b1] = c2 * fkr1; PK[b1 + 1] = c2 * fki1;
        } else {
            f0r[ui0]      = fqr0; f0i[ui0]      = fqi0;
            f0r[ui0 + 16] = fqr1; f0i[ui0 + 16] = fqi1;
            f0r[32 + ui0] = fkr0; f0i[32 + ui0] = fki0;
            f0r[48 + ui0] = fkr1; f0i[48 + ui0] = fki1;
        }
        __syncthreads();
        const float c1 = 0.0078125f;             // 1/128
        if (tid == 0) {
            PQ[960] = c1 * f0r[0];
            PK[960] = c1 * f0r[32];
        } else if (tid <= 15) {
            int u = tid;
            float hr = 0.5f * (f0r[u] + f0r[32 - u]);
            float hi = 0.5f * (f0i[u] - f0i[32 - u]);
            int o = 961 + (u - 1) * 2;
            PQ[o] = c2 * hr; PQ[o + 1] = c2 * hi;
            hr = 0.5f * (f0r[32 + u] + f0r[32 + (32 - u)]);
            hi = 0.5f * (f0i[32 + u] - f0i[32 + (32 - u)]);
            PK[o] = c2 * hr; PK[o + 1] = c2 * hi;
        } else if (tid == 16) {
            // u=16 mode: H[16] = conj(F[u=112])/2, F[112] stored at ui=16
            PQ[991] = c2 * 0.5f * f0r[16]; PQ[992] = -c2 * 0.5f * f0i[16];
            PK[991] = c2 * 0.5f * f0r[48]; PK[992] = -c2 * 0.5f * f0i[48];
        } else if (tid < 48) {
            PQ[993 + (tid - 17)] = 0.f;
            PK[993 + (tid - 17)] = 0.f;
        }
    } else {
        // ---- y image: Fvc = M * icl * Khat (spectral circular conv) ----
        float s = icl[0];
        float khr0 = 0.f, khi0 = 0.f, khr1 = 0.f, khi1 = 0.f;
        #pragma unroll
        for (int a2 = 0; a2 < 5; ++a2) {
            #pragma unroll
            for (int c3 = 0; c3 < 5; ++c3) {
                float kv = ker[a2 * 5 + c3];
                int e0 = (ui0 * (a2 - 2) + v * (c3 - 2)) & 127;  // e^{+i...}
                khr0 = fmaf(kv, ct[e0], khr0);
                khi0 = fmaf(kv, st[e0], khi0);
                int e1 = (u1 * (a2 - 2) + v * (c3 - 2)) & 127;
                khr1 = fmaf(kv, ct[e1], khr1);
                khi1 = fmaf(kv, st[e1], khi1);
            }
        }
        float* FV = ws + FVC_OFF + (size_t)bt * 1024;
        FV[g0 * 2]     = s * (m0r * khr0 - m0i * khi0);
        FV[g0 * 2 + 1] = s * (m0r * khi0 + m0i * khr0);
        FV[g1 * 2]     = s * (m1r * khr1 - m1i * khi1);
        FV[g1 * 2 + 1] = s * (m1r * khi1 + m1i * khr1);
    }
}

// ---------------------------------------------------------------------------
// K2: kx[b,i,j] = exp(-sqrt(||phi_q[b,i]-phi_k[b,j]||^2 + 1e-8)) * mask(i)
// grid: 16 blocks = (b, i-group of 8); block: 256 threads = 8 i x 32 j
// ---------------------------------------------------------------------------
__global__ __launch_bounds__(256) void dist_kernel(
    float* __restrict__ ws, float* __restrict__ out)
{
    __shared__ float lq[8 * 129];
    __shared__ float lk[32 * 129];
    const int tid = threadIdx.x;
    const int b  = blockIdx.x >> 2;
    const int ig = blockIdx.x & 3;
    const int il = tid >> 5;        // 0..7
    const int i  = ig * 8 + il;     // 0..31
    const int j  = tid & 31;

    const float* phq = ws + PHIQ_OFF + (size_t)(b * 32) * 1024;
    const float* phk = ws + PHIK_OFF + (size_t)(b * 32) * 1024;

    float acc = 0.f;
    for (int ch = 0; ch < 8; ++ch) {
        for (int k2 = tid; k2 < 1024; k2 += 256) {
            int r = k2 >> 7, d = k2 & 127;
            lq[r * 129 + d] = phq[(size_t)(ig * 8 + r) * 1024 + ch * 128 + d];
        }
        for (int k2 = tid; k2 < 4096; k2 += 256) {
            int r = k2 >> 7, d = k2 & 127;
            lk[r * 129 + d] = phk[(size_t)r * 1024 + ch * 128 + d];
        }
        __syncthreads();
        const float* qp = lq + il * 129;
        const float* kp = lk + j * 129;
        #pragma unroll 8
        for (int d = 0; d < 128; ++d) {
            float df = qp[d] - kp[d];
            acc = fmaf(df, df, acc);
        }
        __syncthreads();
    }
    float l2  = sqrtf(acc + 1e-8f);
    float kxv = (i == 31) ? 0.f : expf(-l2);
    int o = (b * 32 + i) * 32 + j;
    ws[KX_OFF + o]      = kxv;
    out[OUT_KX_OFF + o] = kxv;
}

// ---------------------------------------------------------------------------
// K3: Fmix[b,q] = sum_i kx[b,i,q] * Fvc[b,i]; inverse restricted transform;
//     write zeros (top half) + attn_y (bottom half) of output.
// grid: 128 blocks = (b,q); block: 256 threads.
// ---------------------------------------------------------------------------
__global__ __launch_bounds__(256) void mix_inv_kernel(
    const float* __restrict__ ws, float* __restrict__ out)
{
    __shared__ float ct[128], st[128];
    __shared__ float fm[1024];
    __shared__ float Ar[128 * 17], Ai[128 * 17];
    __shared__ float kxs[32];

    const int tid = threadIdx.x;
    const int q = blockIdx.x & 31;
    const int b = blockIdx.x >> 5;

    if (tid < 128) {
        float ang = (float)tid * 0.049087385212340517f;
        float s, c;
        sincosf(ang, &s, &c);
        ct[tid] = c; st[tid] = s;
    }
    if (tid < 32) kxs[tid] = ws[KX_OFF + (size_t)(b * 32 + tid) * 32 + q];
    __syncthreads();

    // ---- Phase 1: mix modes ----
    float4 acc = make_float4(0.f, 0.f, 0.f, 0.f);
    const float4* FV = (const float4*)(ws + FVC_OFF) + (size_t)b * 32 * 256;
    for (int i = 0; i < 32; ++i) {   // i=31 has kx=0
        float kv = kxs[i];
        float4 f = FV[(size_t)i * 256 + tid];
        acc.x = fmaf(kv, f.x, acc.x);
        acc.y = fmaf(kv, f.y, acc.y);
        acc.z = fmaf(kv, f.z, acc.z);
        acc.w = fmaf(kv, f.w, acc.w);
    }
    ((float4*)fm)[tid] = acc;
    __syncthreads();

    // ---- Phase 2: A_v(h) = sum_u F[u][v] e^{+2pi i u h/128} ----
    {
        const int h  = tid >> 1;
        const int vb = (tid & 1) * 8;
        float ar[8], ai[8];
        #pragma unroll
        for (int vv = 0; vv < 8; ++vv) { ar[vv] = 0.f; ai[vv] = 0.f; }
        for (int ui = 0; ui < 32; ++ui) {
            int u = (ui < 16) ? ui : (ui + 96);
            int k = (u * h) & 127;
            float cc = ct[k], ss = st[k];
            #pragma unroll
            for (int vv = 0; vv < 8; ++vv) {
                float fr = fm[(ui * 16 + vb + vv) * 2];
                float fi = fm[(ui * 16 + vb + vv) * 2 + 1];
                // (fr + i fi)(cc + i ss)
                ar[vv] = fmaf(fr, cc, fmaf(-fi, ss, ar[vv]));
                ai[vv] = fmaf(fr, ss, fmaf( fi, cc, ai[vv]));
            }
        }
        #pragma unroll
        for (int vv = 0; vv < 8; ++vv) {
            Ar[h * 17 + vb + vv] = ar[vv];
            Ai[h * 17 + vb + vv] = ai[vv];
        }
    }
    __syncthreads();

    // ---- Phase 3: pixels ----
    const int w2   = tid & 127;
    const int hpar = tid >> 7;
    float cw[16], sw[16];
    #pragma unroll
    for (int v = 1; v < 16; ++v) {
        int k = (v * w2) & 127;
        cw[v] = ct[k]; sw[v] = st[k];
    }
    const size_t obase = (size_t)(b * 32 + q) * 256 * 128;
    for (int it = 0; it < 64; ++it) {
        int hh = it * 2 + hpar;
        const float* arp = Ar + hh * 17;
        const float* aip = Ai + hh * 17;
        float accp = arp[0];   // v=0: Re(A_0); Im ignored by irfft
        #pragma unroll
        for (int v = 1; v < 16; ++v)
            accp += 2.f * (arp[v] * cw[v] - aip[v] * sw[v]);
        out[obase + (size_t)hh * 128 + w2] = 0.f;                         // zeros half
        out[obase + (size_t)(128 + hh) * 128 + w2] = accp * 6.103515625e-05f; // /16384
    }
}

extern "C" void kernel_launch(void* const* d_in, const int* in_sizes, int n_in,
                              void* d_out, int out_size, void* d_ws, size_t ws_size,
                              hipStream_t stream)
{
    (void)in_sizes; (void)n_in; (void)out_size; (void)ws_size;
    const float* z    = (const float*)d_in[0];
    const float* qw1r = (const float*)d_in[1];
    const float* qw1i = (const float*)d_in[2];
    const float* qw2r = (const float*)d_in[3];
    const float* qw2i = (const float*)d_in[4];
    const float* kw1r = (const float*)d_in[5];
    const float* kw1i = (const float*)d_in[6];
    const float* kw2r = (const float*)d_in[7];
    const float* kw2i = (const float*)d_in[8];
    const float* icl  = (const float*)d_in[9];
    const float* ker  = (const float*)d_in[10];
    float* ws  = (float*)d_ws;
    float* out = (float*)d_out;

    hipLaunchKernelGGL(fwd_kernel, dim3(256), dim3(256), 0, stream,
                       z, qw1r, qw1i, qw2r, qw2i, kw1r, kw1i, kw2r, kw2i,
                       icl, ker, ws);
    hipLaunchKernelGGL(dist_kernel, dim3(16), dim3(256), 0, stream, ws, out);
    hipLaunchKernelGGL(mix_inv_kernel, dim3(128), dim3(256), 0, stream, ws, out);
}

// Round 2
// 119.402 us; speedup vs baseline: 1.4636x; 1.4636x over previous
//
#include <hip/hip_runtime.h>
#include <math.h>

// Workspace float offsets (ws)
#define FVC_OFF   0          // 128 * 1024
#define PHIQ_OFF  131072     // 128 * 1024
#define PHIK_OFF  262144     // 128 * 1024
#define KX_OFF    393216     // 4096
// G scratch lives in d_out[0 .. 1048576) — consumed by modes_kernel before
// mix_inv_kernel overwrites the whole output. Stream order makes this safe.
#define OUT_KX_OFF 4194304   // kx location in d_out (after 4*32*256*128 floats)

#define TWOPI_128 0.049087385212340517f

// ---------------------------------------------------------------------------
// K1a: row DFT (w -> v modes), radix-4 split. One block = 16 rows of 1 image.
// grid 2048 = 256 images * 8 row-chunks. Writes G[img][v][h] complex to Gout.
// ---------------------------------------------------------------------------
__global__ __launch_bounds__(256) void dft_rows_kernel(
    const float* __restrict__ z, float* __restrict__ Gout)
{
    __shared__ float ct[128], st[128];
    __shared__ float rows[16 * 132];       // stride 132: 16B-aligned, conflict-free
    __shared__ float2 tile[16 * 17];

    const int tid = threadIdx.x;
    const int img = blockIdx.x >> 3;
    const int c0  = blockIdx.x & 7;
    const int bt  = img & 127;
    const int isY = img >> 7;

    if (tid < 128) {
        float s, c;
        sincosf((float)tid * TWOPI_128, &s, &c);
        ct[tid] = c; st[tid] = s;
    }
    const float* xim = z + (size_t)bt * 32768 + (size_t)isY * 16384 + (size_t)c0 * 2048;
    {
        int q0 = tid, q1 = tid + 256;
        float4 a = *(const float4*)(xim + (q0 >> 5) * 128 + (q0 & 31) * 4);
        float4 b = *(const float4*)(xim + (q1 >> 5) * 128 + (q1 & 31) * 4);
        *(float4*)(rows + (q0 >> 5) * 132 + (q0 & 31) * 4) = a;
        *(float4*)(rows + (q1 >> 5) * 132 + (q1 & 31) * 4) = b;
    }
    __syncthreads();

    const int v  = tid & 15;
    const int hl = tid >> 4;
    float sr0 = 0.f, si0 = 0.f, sr1 = 0.f, si1 = 0.f;
    float sr2 = 0.f, si2 = 0.f, sr3 = 0.f, si3 = 0.f;
    const float4* rp = (const float4*)(rows + hl * 132);
    #pragma unroll 8
    for (int m = 0; m < 32; ++m) {
        float4 x4 = rp[m];
        int k = (v * m * 4) & 127;
        float c = ct[k], s = st[k];
        sr0 = fmaf(x4.x, c, sr0); si0 = fmaf(x4.x, s, si0);
        sr1 = fmaf(x4.y, c, sr1); si1 = fmaf(x4.y, s, si1);
        sr2 = fmaf(x4.z, c, sr2); si2 = fmaf(x4.z, s, si2);
        sr3 = fmaf(x4.w, c, sr3); si3 = fmaf(x4.w, s, si3);
    }
    // combine: G = sum_j (sr_j - i si_j) * (cos(v j th) - i sin(v j th))
    float c1 = ct[v], s1 = st[v];
    float c2 = ct[(2 * v) & 127], s2 = st[(2 * v) & 127];
    float c3 = ct[(3 * v) & 127], s3 = st[(3 * v) & 127];
    float gr = sr0 + sr1 * c1 - si1 * s1 + sr2 * c2 - si2 * s2 + sr3 * c3 - si3 * s3;
    float gi = -(si0 + sr1 * s1 + si1 * c1 + sr2 * s2 + si2 * c2 + sr3 * s3 + si3 * c3);

    tile[v * 17 + hl] = make_float2(gr, gi);
    __syncthreads();
    const int vw = tid >> 4, hw = tid & 15;
    float2 val = tile[vw * 17 + hw];
    *(float2*)(Gout + (size_t)img * 4096 + vw * 256 + (c0 * 16 + hw) * 2) = val;
}

// ---------------------------------------------------------------------------
// K1b: column DFT (h -> u modes, u in {0..15, 112..127}), weights / phi / conv.
// grid 256 = one image per block. Reads G from Gglob (d_out scratch).
// ---------------------------------------------------------------------------
__global__ __launch_bounds__(256) void modes_kernel(
    const float* __restrict__ Gglob,
    const float* __restrict__ qw1r, const float* __restrict__ qw1i,
    const float* __restrict__ qw2r, const float* __restrict__ qw2i,
    const float* __restrict__ kw1r, const float* __restrict__ kw1i,
    const float* __restrict__ kw2r, const float* __restrict__ kw2i,
    const float* __restrict__ icl,  const float* __restrict__ ker,
    float* __restrict__ ws)
{
    __shared__ float ct[128], st[128];
    __shared__ float Gbuf[16 * 260];       // per-v rows of 256 floats, pad 4
    __shared__ float f0r[64], f0i[64];

    const int tid = threadIdx.x;
    const int img = blockIdx.x;
    const int bt  = img & 127;
    const int isY = img >> 7;

    if (tid < 128) {
        float s, c;
        sincosf((float)tid * TWOPI_128, &s, &c);
        ct[tid] = c; st[tid] = s;
    }
    const float* gsrc = Gglob + (size_t)img * 4096;
    #pragma unroll
    for (int it = 0; it < 4; ++it) {
        int q = tid + it * 256;
        float4 val = *(const float4*)(gsrc + q * 4);
        *(float4*)(Gbuf + (q >> 6) * 260 + (q & 63) * 4) = val;
    }
    __syncthreads();

    const int v  = tid & 15;
    const int ui = tid >> 4;       // u0 = ui, u1 = ui + 112
    const int u1 = ui + 112;

    float s0r[4] = {0.f, 0.f, 0.f, 0.f}, s0i[4] = {0.f, 0.f, 0.f, 0.f};
    float s1r[4] = {0.f, 0.f, 0.f, 0.f}, s1i[4] = {0.f, 0.f, 0.f, 0.f};
    const float4* gp = (const float4*)(Gbuf + v * 260);
    #pragma unroll 8
    for (int m = 0; m < 32; ++m) {
        float4 ga = gp[2 * m];       // h = 4m, 4m+1 (re,im,re,im)
        float4 gb = gp[2 * m + 1];   // h = 4m+2, 4m+3
        int k0 = (ui * 4 * m) & 127;
        int k1 = (k0 + 64 * m) & 127;
        float c0 = ct[k0], s0 = st[k0];
        float c1 = ct[k1], s1v = st[k1];
        // (gr + i gi)(c - i s) = (gr c + gi s) + i (gi c - gr s)
        s0r[0] = fmaf(ga.x, c0, fmaf(ga.y,  s0, s0r[0]));
        s0i[0] = fmaf(ga.y, c0, fmaf(-ga.x, s0, s0i[0]));
        s0r[1] = fmaf(ga.z, c0, fmaf(ga.w,  s0, s0r[1]));
        s0i[1] = fmaf(ga.w, c0, fmaf(-ga.z, s0, s0i[1]));
        s0r[2] = fmaf(gb.x, c0, fmaf(gb.y,  s0, s0r[2]));
        s0i[2] = fmaf(gb.y, c0, fmaf(-gb.x, s0, s0i[2]));
        s0r[3] = fmaf(gb.z, c0, fmaf(gb.w,  s0, s0r[3]));
        s0i[3] = fmaf(gb.w, c0, fmaf(-gb.z, s0, s0i[3]));
        s1r[0] = fmaf(ga.x, c1, fmaf(ga.y,  s1v, s1r[0]));
        s1i[0] = fmaf(ga.y, c1, fmaf(-ga.x, s1v, s1i[0]));
        s1r[1] = fmaf(ga.z, c1, fmaf(ga.w,  s1v, s1r[1]));
        s1i[1] = fmaf(ga.w, c1, fmaf(-ga.z, s1v, s1i[1]));
        s1r[2] = fmaf(gb.x, c1, fmaf(gb.y,  s1v, s1r[2]));
        s1i[2] = fmaf(gb.y, c1, fmaf(-gb.x, s1v, s1i[2]));
        s1r[3] = fmaf(gb.z, c1, fmaf(gb.w,  s1v, s1r[3]));
        s1i[3] = fmaf(gb.w, c1, fmaf(-gb.z, s1v, s1i[3]));
    }
    float m0r = s0r[0], m0i = s0i[0], m1r = s1r[0], m1i = s1i[0];
    #pragma unroll
    for (int j = 1; j < 4; ++j) {
        int b0 = (ui * j) & 127;
        float cb = ct[b0], sb = st[b0];
        m0r += s0r[j] * cb + s0i[j] * sb;
        m0i += s0i[j] * cb - s0r[j] * sb;
        int b1 = (u1 * j) & 127;
        cb = ct[b1]; sb = st[b1];
        m1r += s1r[j] * cb + s1i[j] * sb;
        m1i += s1i[j] * cb - s1r[j] * sb;
    }

    const int mi = ui * 16 + v;

    if (!isY) {
        float a = qw1r[mi], bq = qw1i[mi];
        float fqr0 = m0r * a - m0i * bq;
        float fqi0 = m0r * bq + m0i * a;
        a = qw2r[mi]; bq = qw2i[mi];
        float fqr1 = m1r * a - m1i * bq;
        float fqi1 = m1r * bq + m1i * a;
        a = kw1r[mi]; bq = kw1i[mi];
        float fkr0 = m0r * a - m0i * bq;
        float fki0 = m0r * bq + m0i * a;
        a = kw2r[mi]; bq = kw2i[mi];
        float fkr1 = m1r * a - m1i * bq;
        float fki1 = m1r * bq + m1i * a;

        float* PQ = ws + PHIQ_OFF + (size_t)bt * 1024;
        float* PK = ws + PHIK_OFF + (size_t)bt * 1024;
        const float c2 = 0.011048543456039806f;  // sqrt(2)/128
        if (v >= 1) {
            int b0 = ((v - 1) * 32 + ui) * 2;
            int b1 = ((v - 1) * 32 + ui + 16) * 2;
            PQ[b0] = c2 * fqr0; PQ[b0 + 1] = c2 * fqi0;
            PQ[b1] = c2 * fqr1; PQ[b1 + 1] = c2 * fqi1;
            PK[b0] = c2 * fkr0; PK[b0 + 1] = c2 * fki0;
            PK[b1] = c2 * fkr1; PK[b1 + 1] = c2 * fki1;
        } else {
            f0r[ui]      = fqr0; f0i[ui]      = fqi0;
            f0r[ui + 16] = fqr1; f0i[ui + 16] = fqi1;
            f0r[32 + ui] = fkr0; f0i[32 + ui] = fki0;
            f0r[48 + ui] = fkr1; f0i[48 + ui] = fki1;
        }
        __syncthreads();
        const float c1n = 0.0078125f;            // 1/128
        if (tid == 0) {
            PQ[960] = c1n * f0r[0];
            PK[960] = c1n * f0r[32];
        } else if (tid <= 15) {
            int u = tid;
            float hr = 0.5f * (f0r[u] + f0r[32 - u]);
            float hi = 0.5f * (f0i[u] - f0i[32 - u]);
            int o = 961 + (u - 1) * 2;
            PQ[o] = c2 * hr; PQ[o + 1] = c2 * hi;
            hr = 0.5f * (f0r[32 + u] + f0r[32 + (32 - u)]);
            hi = 0.5f * (f0i[32 + u] - f0i[32 + (32 - u)]);
            PK[o] = c2 * hr; PK[o + 1] = c2 * hi;
        } else if (tid == 16) {
            PQ[991] = c2 * 0.5f * f0r[16]; PQ[992] = -c2 * 0.5f * f0i[16];
            PK[991] = c2 * 0.5f * f0r[48]; PK[992] = -c2 * 0.5f * f0i[48];
        } else if (tid < 48) {
            PQ[993 + (tid - 17)] = 0.f;
            PK[993 + (tid - 17)] = 0.f;
        }
    } else {
        float s = icl[0];
        float khr0 = 0.f, khi0 = 0.f, khr1 = 0.f, khi1 = 0.f;
        #pragma unroll
        for (int a2 = 0; a2 < 5; ++a2) {
            #pragma unroll
            for (int c3 = 0; c3 < 5; ++c3) {
                float kv = ker[a2 * 5 + c3];
                int e0 = (ui * (a2 - 2) + v * (c3 - 2)) & 127;
                khr0 = fmaf(kv, ct[e0], khr0);
                khi0 = fmaf(kv, st[e0], khi0);
                int e1 = (u1 * (a2 - 2) + v * (c3 - 2)) & 127;
                khr1 = fmaf(kv, ct[e1], khr1);
                khi1 = fmaf(kv, st[e1], khi1);
            }
        }
        const int g0 = mi;
        const int g1 = (ui + 16) * 16 + v;
        float* FV = ws + FVC_OFF + (size_t)bt * 1024;
        FV[g0 * 2]     = s * (m0r * khr0 - m0i * khi0);
        FV[g0 * 2 + 1] = s * (m0r * khi0 + m0i * khr0);
        FV[g1 * 2]     = s * (m1r * khr1 - m1i * khi1);
        FV[g1 * 2 + 1] = s * (m1r * khi1 + m1i * khr1);
    }
}

// ---------------------------------------------------------------------------
// K2: kx[b,i,j] = exp(-sqrt(||phi_q[b,i]-phi_k[b,j]||^2 + 1e-8)) * mask(i)
// grid 128 = (b,i); block 256 = 32 j * 8 d-segments; shuffle-reduce.
// ---------------------------------------------------------------------------
__global__ __launch_bounds__(256) void dist_kernel(
    float* __restrict__ ws, float* __restrict__ out)
{
    __shared__ float lq[8 * 132];
    const int tid = threadIdx.x;
    const int b = blockIdx.x >> 5;
    const int i = blockIdx.x & 31;

    const float* phq = ws + PHIQ_OFF + (size_t)(b * 32 + i) * 1024;
    {
        float4 val = *(const float4*)(phq + tid * 4);
        *(float4*)(lq + (tid >> 5) * 132 + (tid & 31) * 4) = val;
    }
    __syncthreads();

    const int j = tid >> 3, seg = tid & 7;
    const float4* kp = (const float4*)(ws + PHIK_OFF + (size_t)(b * 32 + j) * 1024) + seg * 32;
    const float4* qp = (const float4*)(lq + seg * 132);
    float acc = 0.f;
    #pragma unroll 8
    for (int t = 0; t < 32; ++t) {
        float4 kv = kp[t], qv = qp[t];
        float d0 = qv.x - kv.x, d1 = qv.y - kv.y;
        float d2 = qv.z - kv.z, d3 = qv.w - kv.w;
        acc = fmaf(d0, d0, acc); acc = fmaf(d1, d1, acc);
        acc = fmaf(d2, d2, acc); acc = fmaf(d3, d3, acc);
    }
    acc += __shfl_xor(acc, 1);
    acc += __shfl_xor(acc, 2);
    acc += __shfl_xor(acc, 4);
    if (seg == 0) {
        float l2  = sqrtf(acc + 1e-8f);
        float kxv = (i == 31) ? 0.f : expf(-l2);
        int o = (b * 32 + i) * 32 + j;
        ws[KX_OFF + o]      = kxv;
        out[OUT_KX_OFF + o] = kxv;
    }
}

// ---------------------------------------------------------------------------
// K3: Fmix = sum_i kx[b,i,q] * Fvc[b,i]; inverse restricted transform.
// grid 256 = (b, q, h-half); block 256.
// ---------------------------------------------------------------------------
__global__ __launch_bounds__(256) void mix_inv_kernel(
    const float* __restrict__ ws, float* __restrict__ out)
{
    __shared__ float ct[128], st[128];
    __shared__ float fm[1024];
    __shared__ float Ar[64 * 17], Ai[64 * 17];
    __shared__ float kxs[32];

    const int tid  = threadIdx.x;
    const int b    = blockIdx.x >> 6;
    const int q    = (blockIdx.x >> 1) & 31;
    const int half = blockIdx.x & 1;

    if (tid < 128) {
        float s, c;
        sincosf((float)tid * TWOPI_128, &s, &c);
        ct[tid] = c; st[tid] = s;
    }
    if (tid < 32) kxs[tid] = ws[KX_OFF + (size_t)(b * 32 + tid) * 32 + q];
    __syncthreads();

    // mix modes (i = 31 has kx = 0, skip)
    float4 acc = make_float4(0.f, 0.f, 0.f, 0.f);
    const float4* FV = (const float4*)(ws + FVC_OFF) + (size_t)b * 32 * 256;
    for (int i = 0; i < 31; ++i) {
        float kv = kxs[i];
        float4 f = FV[(size_t)i * 256 + tid];
        acc.x = fmaf(kv, f.x, acc.x);
        acc.y = fmaf(kv, f.y, acc.y);
        acc.z = fmaf(kv, f.z, acc.z);
        acc.w = fmaf(kv, f.w, acc.w);
    }
    ((float4*)fm)[tid] = acc;
    __syncthreads();

    // A_v(h) for our 64 h's
    {
        const int hl = tid >> 2;
        const int vb = (tid & 3) * 4;
        const int h  = half * 64 + hl;
        float ar[4] = {0.f, 0.f, 0.f, 0.f}, ai[4] = {0.f, 0.f, 0.f, 0.f};
        #pragma unroll 4
        for (int ui2 = 0; ui2 < 32; ++ui2) {
            int u = (ui2 < 16) ? ui2 : ui2 + 96;
            int k = (u * h) & 127;
            float cc = ct[k], ss = st[k];
            const float4* fp = (const float4*)(fm + (ui2 * 16 + vb) * 2);
            float4 f01 = fp[0], f23 = fp[1];
            ar[0] = fmaf(f01.x, cc, fmaf(-f01.y, ss, ar[0]));
            ai[0] = fmaf(f01.x, ss, fmaf( f01.y, cc, ai[0]));
            ar[1] = fmaf(f01.z, cc, fmaf(-f01.w, ss, ar[1]));
            ai[1] = fmaf(f01.z, ss, fmaf( f01.w, cc, ai[1]));
            ar[2] = fmaf(f23.x, cc, fmaf(-f23.y, ss, ar[2]));
            ai[2] = fmaf(f23.x, ss, fmaf( f23.y, cc, ai[2]));
            ar[3] = fmaf(f23.z, cc, fmaf(-f23.w, ss, ar[3]));
            ai[3] = fmaf(f23.z, ss, fmaf( f23.w, cc, ai[3]));
        }
        #pragma unroll
        for (int vv = 0; vv < 4; ++vv) {
            Ar[hl * 17 + vb + vv] = ar[vv];
            Ai[hl * 17 + vb + vv] = ai[vv];
        }
    }
    __syncthreads();

    // pixels for our 64 rows
    const int w2   = tid & 127;
    const int hpar = tid >> 7;
    float cw[16], sw[16];
    #pragma unroll
    for (int v = 1; v < 16; ++v) {
        int k = (v * w2) & 127;
        cw[v] = ct[k]; sw[v] = st[k];
    }
    const size_t obase = (size_t)(b * 32 + q) * 32768;
    for (int it = 0; it < 32; ++it) {
        int l = it * 2 + hpar;
        int r = half * 64 + l;
        const float* arp = Ar + l * 17;
        const float* aip = Ai + l * 17;
        float accp = arp[0];
        #pragma unroll
        for (int v = 1; v < 16; ++v)
            accp += 2.f * (arp[v] * cw[v] - aip[v] * sw[v]);
        out[obase + (size_t)r * 128 + w2] = 0.f;
        out[obase + (size_t)(128 + r) * 128 + w2] = accp * 6.103515625e-05f;
    }
}

extern "C" void kernel_launch(void* const* d_in, const int* in_sizes, int n_in,
                              void* d_out, int out_size, void* d_ws, size_t ws_size,
                              hipStream_t stream)
{
    (void)in_sizes; (void)n_in; (void)out_size; (void)ws_size;
    const float* z    = (const float*)d_in[0];
    const float* qw1r = (const float*)d_in[1];
    const float* qw1i = (const float*)d_in[2];
    const float* qw2r = (const float*)d_in[3];
    const float* qw2i = (const float*)d_in[4];
    const float* kw1r = (const float*)d_in[5];
    const float* kw1i = (const float*)d_in[6];
    const float* kw2r = (const float*)d_in[7];
    const float* kw2i = (const float*)d_in[8];
    const float* icl  = (const float*)d_in[9];
    const float* ker  = (const float*)d_in[10];
    float* ws  = (float*)d_ws;
    float* out = (float*)d_out;

    // G scratch in d_out (first 4 MB), consumed before K3 overwrites output.
    hipLaunchKernelGGL(dft_rows_kernel, dim3(2048), dim3(256), 0, stream, z, out);
    hipLaunchKernelGGL(modes_kernel, dim3(256), dim3(256), 0, stream,
                       out, qw1r, qw1i, qw2r, qw2i, kw1r, kw1i, kw2r, kw2i,
                       icl, ker, ws);
    hipLaunchKernelGGL(dist_kernel, dim3(128), dim3(256), 0, stream, ws, out);
    hipLaunchKernelGGL(mix_inv_kernel, dim3(256), dim3(256), 0, stream, ws, out);
}